// Round 9
// baseline (48.910 us; speedup 1.0000x reference)
//
#include <hip/hip_runtime.h>
#include <hip/hip_bf16.h>
#include <stdint.h>

// B=2, L=256, CB=64, D=512, H=8, HD=64. BI = B*L = 512.
// Pipeline (5 launches; ~17us fixed replay overhead + ~5.3us pair read are structural):
//   K0 (64 blk):  MkT[hc][e] bf16 (pre-scaled 0.125) + Cb[hc] f32 (pre-scaled)
//   G1 (256 blk): qk[bi][hc] bf16 = x @ Mk_s + Cb  (tile 32x32, K=512)
//   K2 (578 blk): blocks 0..63  -> MvT[f][hc] bf16 (Wv@Wo per head, MFMA)
//                 blocks 64..65 -> bvoSum[f] = bv@Wo + bo (f32)
//                 blocks 66..577-> per (b,i): pair staged once -> scores MFMA ->
//                                  softmax (no max-sub) -> wp MFMA -> bf16 wp
//   G2 (256 blk): GP[bi][f] f32 = wp @ Mv (tile 32x32, K=512)
//   K4 (512 blk): LayerNorm(GP + bvoSum + x)
//
// ws (f32 offsets): MkT@0 (131072 u32) | MvT@131072 | Cb@262144 | bvoSum@262656 |
//   qk@263168 (131072 u32) | wp@394240 (131072 u32) | GP@525312 (262144 f32)

using u32   = unsigned int;
using s8bf  = __attribute__((ext_vector_type(8))) short;
using f32x4 = __attribute__((ext_vector_type(4))) float;

union U4 { uint4 u; s8bf v; };

__device__ __forceinline__ u32 pack2(float a, float b) {
  __hip_bfloat162 h2 = __float22bfloat162_rn(make_float2(a, b));
  union { __hip_bfloat162 h; u32 u; } cv; cv.h = h2; return cv.u;
}
__device__ __forceinline__ ushort bf16r(float f) {
  u32 u = __float_as_uint(f);
  return (ushort)((u + 0x7fffu + ((u >> 16) & 1u)) >> 16);
}
__device__ __forceinline__ float ubf(ushort s) {
  return __uint_as_float(((u32)s) << 16);
}

// ---------------- K0: Mk prep (MFMA bf16) ----------------
// 64 blocks: h = bid>>3, e-tile = (bid&7)*64. MkT[hc][e] scaled 0.125; Cb scaled.
__global__ __launch_bounds__(256) void k0_prep(
    const float* __restrict__ Wq, const float* __restrict__ bq,
    const float* __restrict__ Wk,
    u32* __restrict__ MkT, float* __restrict__ Cb) {
  __shared__ ushort LA[64 * 72];
  __shared__ ushort LB[64 * 72];
  __shared__ float bvec[64];
  const int t = threadIdx.x;
  const int bid = blockIdx.x;
  const int h = bid >> 3;
  const int tile = (bid & 7) * 64;

  {
    int row = t >> 2, q = t & 3;
    const float* Arow = Wq + (size_t)(tile + row) * 512 + h * 64;
    #pragma unroll
    for (int i = 0; i < 4; ++i) {
      int d0 = q * 4 + i * 16;
      float4 v = *(const float4*)(Arow + d0);
      *(uint2*)&LA[row * 72 + d0] = make_uint2(pack2(v.x, v.y), pack2(v.z, v.w));
    }
  }
  {
    int row = t >> 2, q = t & 3;
    const float* Brow = Wk + (size_t)row * 512 + h * 64;
    #pragma unroll
    for (int i = 0; i < 4; ++i) {
      int d0 = q * 4 + i * 16;
      float4 v = *(const float4*)(Brow + d0);
      *(uint2*)&LB[row * 72 + d0] = make_uint2(pack2(v.x, v.y), pack2(v.z, v.w));
    }
  }
  if (t < 16) {
    float4 v = *(const float4*)&bq[h * 64 + t * 4];
    bvec[t * 4 + 0] = v.x; bvec[t * 4 + 1] = v.y;
    bvec[t * 4 + 2] = v.z; bvec[t * 4 + 3] = v.w;
  }
  __syncthreads();

  const int lane = t & 63, w = t >> 6;
  const int lr = lane & 15, lg = lane >> 4;
  f32x4 acc[4] = {};
  #pragma unroll
  for (int kk = 0; kk < 2; ++kk) {
    U4 a; a.u = *(const uint4*)&LA[(w * 16 + lr) * 72 + kk * 32 + lg * 8];
    #pragma unroll
    for (int nt = 0; nt < 4; ++nt) {
      U4 b; b.u = *(const uint4*)&LB[(nt * 16 + lr) * 72 + kk * 32 + lg * 8];
      acc[nt] = __builtin_amdgcn_mfma_f32_16x16x32_bf16(a.v, b.v, acc[nt], 0, 0, 0);
    }
  }
  #pragma unroll
  for (int nt = 0; nt < 4; ++nt) {
    int hc = h * 64 + nt * 16 + lr;
    int e0 = tile + w * 16 + lg * 4;
    uint2 o = make_uint2(pack2(acc[nt][0] * 0.125f, acc[nt][1] * 0.125f),
                         pack2(acc[nt][2] * 0.125f, acc[nt][3] * 0.125f));
    *(uint2*)&MkT[(size_t)hc * 256 + (e0 >> 1)] = o;
  }
  if ((bid & 7) == 0 && t < 64) {
    float s = 0.f;
    #pragma unroll 16
    for (int d = 0; d < 64; ++d) s += bvec[d] * ubf(LB[t * 72 + d]);
    Cb[h * 64 + t] = s * 0.125f;
  }
}

// ---------------- G1: qk bf16 = x @ Mk_s + Cb, tile 32x32, K=512 ----------------
__global__ __launch_bounds__(256) void k_g1(
    const float* __restrict__ x, const u32* __restrict__ MkT,
    const float* __restrict__ Cb, u32* __restrict__ qk) {
  __shared__ ushort As[32 * 136];
  __shared__ ushort Bs[32 * 136];
  const int t = threadIdx.x;
  const int n0 = blockIdx.x * 32;   // hc
  const int m0 = blockIdx.y * 32;   // bi
  const int lane = t & 63, w = t >> 6;
  const int lr = lane & 15, lg = lane >> 4;
  const int mh = w & 1, nh = w >> 1;
  const int row = t >> 3, q = t & 7;
  f32x4 acc = {0.f, 0.f, 0.f, 0.f};
  for (int kc = 0; kc < 4; ++kc) {
    {
      const float* xp = x + (size_t)(m0 + row) * 512 + kc * 128 + q * 16;
      float4 v0 = *(const float4*)xp,       v1 = *(const float4*)(xp + 4);
      float4 v2 = *(const float4*)(xp + 8), v3 = *(const float4*)(xp + 12);
      *(uint4*)&As[row * 136 + q * 16] =
          make_uint4(pack2(v0.x, v0.y), pack2(v0.z, v0.w),
                     pack2(v1.x, v1.y), pack2(v1.z, v1.w));
      *(uint4*)&As[row * 136 + q * 16 + 8] =
          make_uint4(pack2(v2.x, v2.y), pack2(v2.z, v2.w),
                     pack2(v3.x, v3.y), pack2(v3.z, v3.w));
    }
    {
      const uint4* B4 = (const uint4*)MkT + (size_t)(n0 + row) * 64 + kc * 16 + q * 2;
      *(uint4*)&Bs[row * 136 + q * 16]     = B4[0];
      *(uint4*)&Bs[row * 136 + q * 16 + 8] = B4[1];
    }
    __syncthreads();
    #pragma unroll
    for (int kk = 0; kk < 4; ++kk) {
      U4 a; a.u = *(const uint4*)&As[(mh * 16 + lr) * 136 + kk * 32 + lg * 8];
      U4 b; b.u = *(const uint4*)&Bs[(nh * 16 + lr) * 136 + kk * 32 + lg * 8];
      acc = __builtin_amdgcn_mfma_f32_16x16x32_bf16(a.v, b.v, acc, 0, 0, 0);
    }
    __syncthreads();
  }
  const int n = n0 + nh * 16 + lr;
  const float cb = Cb[n];
  float v[4], prt[4];
  #pragma unroll
  for (int r = 0; r < 4; ++r) {
    v[r] = acc[r] + cb;
    prt[r] = __shfl_xor(v[r], 1, 64);
  }
  if ((lane & 1) == 0) {
    #pragma unroll
    for (int r = 0; r < 4; ++r)
      qk[(size_t)(m0 + mh * 16 + lg * 4 + r) * 256 + (n >> 1)] = pack2(v[r], prt[r]);
  }
}

// ---------------- K2: Mv-prep (64) + bvoSum (2) + attention (512) ----------------
struct SA { u32 PuU[256 * 36]; u32 PtU[64 * 132]; float redz[16][4]; };
struct SM { ushort LA[64 * 72]; ushort LB[64 * 72]; };
union SmemK2 { SA a; SM m; };

__global__ __launch_bounds__(256) void k2_attn(
    const float* __restrict__ pair, const u32* __restrict__ qk,
    const float* __restrict__ Wv, const float* __restrict__ Wo,
    const float* __restrict__ bv, const float* __restrict__ bo,
    u32* __restrict__ MvT, float* __restrict__ bvoSum,
    u32* __restrict__ wpg) {
  __shared__ SmemK2 sm;
  const int t = threadIdx.x;
  const int bid = blockIdx.x;
  const int lane = t & 63, w = t >> 6;
  const int lr = lane & 15, lg = lane >> 4;

  if (bid < 64) {
    // ---- MvT[f][hc] = (Wv@Wo per head)^T bf16 ----
    const int h = bid >> 3;
    const int tile = (bid & 7) * 64;   // f-tile
    {
      int row = t >> 2, q = t & 3;
      const float* Arow = Wv + (size_t)row * 512 + h * 64;
      #pragma unroll
      for (int i = 0; i < 4; ++i) {
        int d0 = q * 4 + i * 16;
        float4 v = *(const float4*)(Arow + d0);
        *(uint2*)&sm.m.LA[row * 72 + d0] = make_uint2(pack2(v.x, v.y), pack2(v.z, v.w));
      }
    }
    {
      int d = t >> 2, q = t & 3;
      const float* Brow = Wo + (size_t)(h * 64 + d) * 512 + tile;
      #pragma unroll
      for (int i = 0; i < 4; ++i) {
        int f0 = q * 4 + i * 16;
        float4 v = *(const float4*)(Brow + f0);
        sm.m.LB[(f0 + 0) * 72 + d] = bf16r(v.x);
        sm.m.LB[(f0 + 1) * 72 + d] = bf16r(v.y);
        sm.m.LB[(f0 + 2) * 72 + d] = bf16r(v.z);
        sm.m.LB[(f0 + 3) * 72 + d] = bf16r(v.w);
      }
    }
    __syncthreads();
    f32x4 acc[4] = {};
    #pragma unroll
    for (int kk = 0; kk < 2; ++kk) {
      U4 a; a.u = *(const uint4*)&sm.m.LA[(w * 16 + lr) * 72 + kk * 32 + lg * 8];
      #pragma unroll
      for (int nt = 0; nt < 4; ++nt) {
        U4 b; b.u = *(const uint4*)&sm.m.LB[(nt * 16 + lr) * 72 + kk * 32 + lg * 8];
        acc[nt] = __builtin_amdgcn_mfma_f32_16x16x32_bf16(a.v, b.v, acc[nt], 0, 0, 0);
      }
    }
    #pragma unroll
    for (int nt = 0; nt < 4; ++nt) {
      int f = tile + nt * 16 + lr;
      int hc0 = h * 64 + w * 16 + lg * 4;
      uint2 o = make_uint2(pack2(acc[nt][0], acc[nt][1]),
                           pack2(acc[nt][2], acc[nt][3]));
      *(uint2*)&MvT[(size_t)f * 256 + (hc0 >> 1)] = o;
    }
    return;
  }
  if (bid < 66) {
    // ---- bvoSum[f] = bv @ Wo + bo ----
    const int f = (bid - 64) * 256 + t;
    float s = bo[f];
    #pragma unroll 8
    for (int hd = 0; hd < 512; ++hd)
      s += bv[hd] * Wo[(size_t)hd * 512 + f];
    bvoSum[f] = s;
    return;
  }

  // ---- attention (round-8 proven body) ----
  const int bi = bid - 66;
  const float* pr = pair + (size_t)bi * 16384;

  #pragma unroll
  for (int r = 0; r < 8; ++r) {
    int task = t + 256 * r;
    int jp = task >> 4, cq = task & 15;
    const float* p0 = pr + (size_t)(2 * jp) * 64 + cq * 4;
    float4 a = *(const float4*)p0;
    float4 b = *(const float4*)(p0 + 64);
    *(uint2*)&sm.a.PuU[(2 * jp) * 36 + cq * 2]     = make_uint2(pack2(a.x, a.y), pack2(a.z, a.w));
    *(uint2*)&sm.a.PuU[(2 * jp + 1) * 36 + cq * 2] = make_uint2(pack2(b.x, b.y), pack2(b.z, b.w));
    int c = cq * 4;
    int col = jp ^ ((cq & 7) << 2);
    sm.a.PtU[(c + 0) * 132 + col] = pack2(a.x, b.x);
    sm.a.PtU[(c + 1) * 132 + col] = pack2(a.y, b.y);
    sm.a.PtU[(c + 2) * 132 + col] = pack2(a.z, b.z);
    sm.a.PtU[(c + 3) * 132 + col] = pack2(a.w, b.w);
  }

  U4 bq0, bq1;
  bq0.u = make_uint4(0, 0, 0, 0); bq1.u = make_uint4(0, 0, 0, 0);
  if (lr < 8) {
    const uint4* qrow = (const uint4*)qk + (size_t)bi * 64 + lr * 8 + lg;
    bq0.u = qrow[0];
    bq1.u = qrow[4];
  }
  __syncthreads();

  f32x4 sc[4];
  #pragma unroll
  for (int jt = 0; jt < 4; ++jt) {
    int j0 = w * 64 + jt * 16;
    U4 a0, a1;
    a0.u = *(const uint4*)&sm.a.PuU[(j0 + lr) * 36 + lg * 4];
    a1.u = *(const uint4*)&sm.a.PuU[(j0 + lr) * 36 + 16 + lg * 4];
    f32x4 z = {0.f, 0.f, 0.f, 0.f};
    z = __builtin_amdgcn_mfma_f32_16x16x32_bf16(a0.v, bq0.v, z, 0, 0, 0);
    z = __builtin_amdgcn_mfma_f32_16x16x32_bf16(a1.v, bq1.v, z, 0, 0, 0);
    sc[jt] = z;
  }

  float ev[4][4];
  float es = 0.f;
  #pragma unroll
  for (int jt = 0; jt < 4; ++jt)
    #pragma unroll
    for (int r = 0; r < 4; ++r) { ev[jt][r] = __expf(sc[jt][r]); es += ev[jt][r]; }
  es += __shfl_xor(es, 16, 64);
  es += __shfl_xor(es, 32, 64);
  if (lane < 16) sm.a.redz[lr][w] = es;
  __syncthreads();
  float4 zr = *(const float4*)&sm.a.redz[lr][0];
  float rz = __builtin_amdgcn_rcpf(zr.x + zr.y + zr.z + zr.w);
  ushort* wb = (ushort*)sm.a.PuU;
  #pragma unroll
  for (int jt = 0; jt < 4; ++jt) {
    int j0 = w * 64 + jt * 16 + lg * 4;
    uint2 o = make_uint2(pack2(ev[jt][0] * rz, ev[jt][1] * rz),
                         pack2(ev[jt][2] * rz, ev[jt][3] * rz));
    *(uint2*)&wb[lr * 264 + j0] = o;
  }
  __syncthreads();

  f32x4 wacc = {0.f, 0.f, 0.f, 0.f};
  const int c = w * 16 + lr;
  const int cswz = (c >> 2) & 7;
  #pragma unroll
  for (int ks = 0; ks < 8; ++ks) {
    U4 a; a.u = *(const uint4*)&wb[lr * 264 + ks * 32 + lg * 8];
    int g = ks * 4 + lg;
    U4 b; b.u = *(const uint4*)&sm.a.PtU[c * 132 + ((g ^ cswz) << 2)];
    wacc = __builtin_amdgcn_mfma_f32_16x16x32_bf16(a.v, b.v, wacc, 0, 0, 0);
  }
  float prt[4];
  #pragma unroll
  for (int r = 0; r < 4; ++r) prt[r] = __shfl_xor(wacc[r], 1, 64);
  if (lane < 32 && (lane & 1) == 0) {
    #pragma unroll
    for (int r = 0; r < 4; ++r) {
      int h = lg * 4 + r;
      wpg[(size_t)bi * 256 + h * 32 + (c >> 1)] = pack2(wacc[r], prt[r]);
    }
  }
}

// ---------------- G2: GP f32 = wp @ Mv, tile 32x32, K=512 ----------------
__global__ __launch_bounds__(256) void k_g2(
    const u32* __restrict__ wp, const u32* __restrict__ MvT,
    float* __restrict__ GP) {
  __shared__ ushort As[32 * 136];
  __shared__ ushort Bs[32 * 136];
  const int t = threadIdx.x;
  const int n0 = blockIdx.x * 32;   // f
  const int m0 = blockIdx.y * 32;   // bi
  const int lane = t & 63, w = t >> 6;
  const int lr = lane & 15, lg = lane >> 4;
  const int mh = w & 1, nh = w >> 1;
  const int row = t >> 3, q = t & 7;
  f32x4 acc = {0.f, 0.f, 0.f, 0.f};
  for (int kc = 0; kc < 4; ++kc) {
    {
      const uint4* A4 = (const uint4*)wp + (size_t)(m0 + row) * 64 + kc * 16 + q * 2;
      *(uint4*)&As[row * 136 + q * 16]     = A4[0];
      *(uint4*)&As[row * 136 + q * 16 + 8] = A4[1];
      const uint4* B4 = (const uint4*)MvT + (size_t)(n0 + row) * 64 + kc * 16 + q * 2;
      *(uint4*)&Bs[row * 136 + q * 16]     = B4[0];
      *(uint4*)&Bs[row * 136 + q * 16 + 8] = B4[1];
    }
    __syncthreads();
    #pragma unroll
    for (int kk = 0; kk < 4; ++kk) {
      U4 a; a.u = *(const uint4*)&As[(mh * 16 + lr) * 136 + kk * 32 + lg * 8];
      U4 b; b.u = *(const uint4*)&Bs[(nh * 16 + lr) * 136 + kk * 32 + lg * 8];
      acc = __builtin_amdgcn_mfma_f32_16x16x32_bf16(a.v, b.v, acc, 0, 0, 0);
    }
    __syncthreads();
  }
  const int n = n0 + nh * 16 + lr;
  #pragma unroll
  for (int r = 0; r < 4; ++r)
    GP[(size_t)(m0 + mh * 16 + lg * 4 + r) * 512 + n] = acc[r];
}

// ---------------- K4: residual + bvoSum + LayerNorm ----------------
__global__ __launch_bounds__(256) void k4_ln(
    const float* __restrict__ GP, const float* __restrict__ bvoSum,
    const float* __restrict__ x,
    const float* __restrict__ gamma, const float* __restrict__ beta,
    float* __restrict__ out) {
  __shared__ float red[2][4];
  const int t = threadIdx.x, bi = blockIdx.x;
  const int f = t * 2;
  const size_t base = (size_t)bi * 512 + f;
  float2 y2 = *(const float2*)&GP[base];
  float2 xv = *(const float2*)&x[base];
  float2 bb = *(const float2*)&bvoSum[f];
  y2.x += xv.x + bb.x; y2.y += xv.y + bb.y;
  float s = y2.x + y2.y;
  float q = y2.x * y2.x + y2.y * y2.y;
  for (int o = 32; o; o >>= 1) { s += __shfl_xor(s, o, 64); q += __shfl_xor(q, o, 64); }
  const int wv = t >> 6, lane = t & 63;
  if (lane == 0) { red[0][wv] = s; red[1][wv] = q; }
  __syncthreads();
  float S = red[0][0] + red[0][1] + red[0][2] + red[0][3];
  float Qs = red[1][0] + red[1][1] + red[1][2] + red[1][3];
  float mu = S * (1.f / 512.f);
  float var = Qs * (1.f / 512.f) - mu * mu;
  float rstd = rsqrtf(var + 1e-5f);
  float2 gm = *(const float2*)&gamma[f];
  float2 bt = *(const float2*)&beta[f];
  float2 o2;
  o2.x = (y2.x - mu) * rstd * gm.x + bt.x;
  o2.y = (y2.y - mu) * rstd * gm.y + bt.y;
  *(float2*)&out[base] = o2;
}

extern "C" void kernel_launch(void* const* d_in, const int* in_sizes, int n_in,
                              void* d_out, int out_size, void* d_ws, size_t ws_size,
                              hipStream_t stream) {
  (void)in_sizes; (void)n_in; (void)out_size; (void)ws_size;
  const float* x     = (const float*)d_in[0];
  const float* pair  = (const float*)d_in[1];
  const float* Wq    = (const float*)d_in[2];
  const float* bq    = (const float*)d_in[3];
  const float* Wk    = (const float*)d_in[4];
  // d_in[5] = bk: Q.bk constant over j -> cancels in softmax
  const float* Wv    = (const float*)d_in[6];
  const float* bv    = (const float*)d_in[7];
  const float* Wo    = (const float*)d_in[8];
  const float* bo    = (const float*)d_in[9];
  const float* gamma = (const float*)d_in[10];
  const float* beta  = (const float*)d_in[11];

  float* ws     = (float*)d_ws;
  u32* MkT      = (u32*)ws;
  u32* MvT      = (u32*)ws + 131072;
  float* Cb     = ws + 262144;
  float* bvoSum = ws + 262656;
  u32* qk       = (u32*)(ws + 263168);
  u32* wp       = (u32*)(ws + 394240);
  float* GP     = ws + 525312;

  k0_prep<<<64, 256, 0, stream>>>(Wq, bq, Wk, MkT, Cb);
  k_g1<<<dim3(16, 16), 256, 0, stream>>>(x, MkT, Cb, qk);
  k2_attn<<<578, 256, 0, stream>>>(pair, qk, Wv, Wo, bv, bo, MvT, bvoSum, wp);
  k_g2<<<dim3(16, 16), 256, 0, stream>>>(wp, MvT, GP);
  k4_ln<<<512, 256, 0, stream>>>(GP, bvoSum, x, gamma, beta, (float*)d_out);
}

// Round 10
// 31.790 us; speedup vs baseline: 1.5385x; 1.5385x over previous
//
#include <hip/hip_runtime.h>
#include <hip/hip_bf16.h>
#include <stdint.h>

// B=2, L=256, CB=64, D=512, H=8, HD=64. BI = B*L = 512.
// Pipeline (5 launches; ~17us fixed replay overhead + ~5.3us pair read are structural):
//   K0 (64 blk):  MkT[hc][e] bf16 (pre-scaled 0.125) + Cb[hc] f32 (pre-scaled)
//   G1 (320 blk): bid<256: qk[bi][hc] bf16 = x @ Mk_s + Cb (tile 32x32, K=512)
//                 bid>=256: MvT[f][hc] bf16 (Wv@Wo per head, MFMA) + bvoP[8][512]
//   K2 (512 blk): per (b,i): pair staged once -> scores MFMA (qk direct bf16) ->
//                 softmax (no max-sub) -> wp MFMA -> shfl-pack bf16 wp
//   G2 (256 blk): GP[bi][f] f32 = wp @ Mv (tile 32x32, K=512)
//   K4 (512 blk): LayerNorm(GP + bo + sum_h bvoP + x)
//
// ws (f32 offsets): MkT@0 (131072 u32) | MvT@131072 | Cb@262144 | bvoP@262656 |
//   qk@266752 (131072 u32) | wp@397824 (131072 u32) | GP@528896 (262144 f32)

using u32   = unsigned int;
using s8bf  = __attribute__((ext_vector_type(8))) short;
using f32x4 = __attribute__((ext_vector_type(4))) float;

union U4 { uint4 u; s8bf v; };

__device__ __forceinline__ u32 pack2(float a, float b) {
  __hip_bfloat162 h2 = __float22bfloat162_rn(make_float2(a, b));
  union { __hip_bfloat162 h; u32 u; } cv; cv.h = h2; return cv.u;
}
__device__ __forceinline__ ushort bf16r(float f) {
  u32 u = __float_as_uint(f);
  return (ushort)((u + 0x7fffu + ((u >> 16) & 1u)) >> 16);
}
__device__ __forceinline__ float ubf(ushort s) {
  return __uint_as_float(((u32)s) << 16);
}

// ---------------- K0: Mk prep (MFMA bf16), 64 blocks ----------------
__global__ __launch_bounds__(256) void k0_prep(
    const float* __restrict__ Wq, const float* __restrict__ bq,
    const float* __restrict__ Wk,
    u32* __restrict__ MkT, float* __restrict__ Cb) {
  __shared__ ushort LA[64 * 72];
  __shared__ ushort LB[64 * 72];
  __shared__ float bvec[64];
  const int t = threadIdx.x;
  const int bid = blockIdx.x;
  const int h = bid >> 3;
  const int tile = (bid & 7) * 64;

  {
    int row = t >> 2, q = t & 3;
    const float* Arow = Wq + (size_t)(tile + row) * 512 + h * 64;
    #pragma unroll
    for (int i = 0; i < 4; ++i) {
      int d0 = q * 4 + i * 16;
      float4 v = *(const float4*)(Arow + d0);
      *(uint2*)&LA[row * 72 + d0] = make_uint2(pack2(v.x, v.y), pack2(v.z, v.w));
    }
  }
  {
    int row = t >> 2, q = t & 3;
    const float* Brow = Wk + (size_t)row * 512 + h * 64;
    #pragma unroll
    for (int i = 0; i < 4; ++i) {
      int d0 = q * 4 + i * 16;
      float4 v = *(const float4*)(Brow + d0);
      *(uint2*)&LB[row * 72 + d0] = make_uint2(pack2(v.x, v.y), pack2(v.z, v.w));
    }
  }
  if (t < 16) {
    float4 v = *(const float4*)&bq[h * 64 + t * 4];
    bvec[t * 4 + 0] = v.x; bvec[t * 4 + 1] = v.y;
    bvec[t * 4 + 2] = v.z; bvec[t * 4 + 3] = v.w;
  }
  __syncthreads();

  const int lane = t & 63, w = t >> 6;
  const int lr = lane & 15, lg = lane >> 4;
  f32x4 acc[4] = {};
  #pragma unroll
  for (int kk = 0; kk < 2; ++kk) {
    U4 a; a.u = *(const uint4*)&LA[(w * 16 + lr) * 72 + kk * 32 + lg * 8];
    #pragma unroll
    for (int nt = 0; nt < 4; ++nt) {
      U4 b; b.u = *(const uint4*)&LB[(nt * 16 + lr) * 72 + kk * 32 + lg * 8];
      acc[nt] = __builtin_amdgcn_mfma_f32_16x16x32_bf16(a.v, b.v, acc[nt], 0, 0, 0);
    }
  }
  #pragma unroll
  for (int nt = 0; nt < 4; ++nt) {
    int hc = h * 64 + nt * 16 + lr;
    int e0 = tile + w * 16 + lg * 4;
    uint2 o = make_uint2(pack2(acc[nt][0] * 0.125f, acc[nt][1] * 0.125f),
                         pack2(acc[nt][2] * 0.125f, acc[nt][3] * 0.125f));
    *(uint2*)&MkT[(size_t)hc * 256 + (e0 >> 1)] = o;
  }
  if ((bid & 7) == 0 && t < 64) {
    float s = 0.f;
    #pragma unroll 16
    for (int d = 0; d < 64; ++d) s += bvec[d] * ubf(LB[t * 72 + d]);
    Cb[h * 64 + t] = s * 0.125f;
  }
}

// ---------------- G1: qk GEMM (256 blk) + Mv/bvoP prep (64 blk) ----------------
struct SG { ushort As[32 * 136]; ushort Bs[32 * 136]; };
struct SM { ushort LA[64 * 72]; ushort LB[64 * 72]; float bvec[64]; };
union SmemG1 { SG g; SM m; };

__global__ __launch_bounds__(256) void k_g1(
    const float* __restrict__ x, const u32* __restrict__ MkT,
    const float* __restrict__ Cb,
    const float* __restrict__ Wv, const float* __restrict__ Wo,
    const float* __restrict__ bv,
    u32* __restrict__ qk, u32* __restrict__ MvT, float* __restrict__ bvoP) {
  __shared__ SmemG1 sm;
  const int t = threadIdx.x;
  const int bid = blockIdx.x;
  const int lane = t & 63, w = t >> 6;
  const int lr = lane & 15, lg = lane >> 4;

  if (bid >= 256) {
    // ---- MvT[f][hc] = (Wv@Wo per head)^T bf16 + bvoP (round-8 K0 Mv body) ----
    const int sub = bid - 256;
    const int h = sub >> 3;
    const int tile = (sub & 7) * 64;   // f-tile
    {
      int row = t >> 2, q = t & 3;
      const float* Arow = Wv + (size_t)row * 512 + h * 64;
      #pragma unroll
      for (int i = 0; i < 4; ++i) {
        int d0 = q * 4 + i * 16;
        float4 v = *(const float4*)(Arow + d0);
        *(uint2*)&sm.m.LA[row * 72 + d0] = make_uint2(pack2(v.x, v.y), pack2(v.z, v.w));
      }
    }
    {
      int d = t >> 2, q = t & 3;
      const float* Brow = Wo + (size_t)(h * 64 + d) * 512 + tile;
      #pragma unroll
      for (int i = 0; i < 4; ++i) {
        int f0 = q * 4 + i * 16;
        float4 v = *(const float4*)(Brow + f0);
        sm.m.LB[(f0 + 0) * 72 + d] = bf16r(v.x);
        sm.m.LB[(f0 + 1) * 72 + d] = bf16r(v.y);
        sm.m.LB[(f0 + 2) * 72 + d] = bf16r(v.z);
        sm.m.LB[(f0 + 3) * 72 + d] = bf16r(v.w);
      }
    }
    if (t < 16) {
      float4 v = *(const float4*)&bv[h * 64 + t * 4];
      sm.m.bvec[t * 4 + 0] = v.x; sm.m.bvec[t * 4 + 1] = v.y;
      sm.m.bvec[t * 4 + 2] = v.z; sm.m.bvec[t * 4 + 3] = v.w;
    }
    __syncthreads();
    f32x4 acc[4] = {};
    #pragma unroll
    for (int kk = 0; kk < 2; ++kk) {
      U4 a; a.u = *(const uint4*)&sm.m.LA[(w * 16 + lr) * 72 + kk * 32 + lg * 8];
      #pragma unroll
      for (int nt = 0; nt < 4; ++nt) {
        U4 b; b.u = *(const uint4*)&sm.m.LB[(nt * 16 + lr) * 72 + kk * 32 + lg * 8];
        acc[nt] = __builtin_amdgcn_mfma_f32_16x16x32_bf16(a.v, b.v, acc[nt], 0, 0, 0);
      }
    }
    #pragma unroll
    for (int nt = 0; nt < 4; ++nt) {
      int f = tile + nt * 16 + lr;
      int hc0 = h * 64 + w * 16 + lg * 4;
      uint2 o = make_uint2(pack2(acc[nt][0], acc[nt][1]),
                           pack2(acc[nt][2], acc[nt][3]));
      *(uint2*)&MvT[(size_t)f * 256 + (hc0 >> 1)] = o;
    }
    if (t < 64) {
      float s = 0.f;
      #pragma unroll 16
      for (int d = 0; d < 64; ++d) s += sm.m.bvec[d] * ubf(sm.m.LB[t * 72 + d]);
      bvoP[h * 512 + tile + t] = s;
    }
    return;
  }

  // ---- qk GEMM (round-8 body): n0 = (bid&15)*32 (hc), m0 = (bid>>4)*32 (bi) ----
  const int n0 = (bid & 15) * 32;
  const int m0 = (bid >> 4) * 32;
  const int mh = w & 1, nh = w >> 1;
  const int row = t >> 3, q = t & 7;
  f32x4 acc = {0.f, 0.f, 0.f, 0.f};
  for (int kc = 0; kc < 4; ++kc) {
    {
      const float* xp = x + (size_t)(m0 + row) * 512 + kc * 128 + q * 16;
      float4 v0 = *(const float4*)xp,       v1 = *(const float4*)(xp + 4);
      float4 v2 = *(const float4*)(xp + 8), v3 = *(const float4*)(xp + 12);
      *(uint4*)&sm.g.As[row * 136 + q * 16] =
          make_uint4(pack2(v0.x, v0.y), pack2(v0.z, v0.w),
                     pack2(v1.x, v1.y), pack2(v1.z, v1.w));
      *(uint4*)&sm.g.As[row * 136 + q * 16 + 8] =
          make_uint4(pack2(v2.x, v2.y), pack2(v2.z, v2.w),
                     pack2(v3.x, v3.y), pack2(v3.z, v3.w));
    }
    {
      const uint4* B4 = (const uint4*)MkT + (size_t)(n0 + row) * 64 + kc * 16 + q * 2;
      *(uint4*)&sm.g.Bs[row * 136 + q * 16]     = B4[0];
      *(uint4*)&sm.g.Bs[row * 136 + q * 16 + 8] = B4[1];
    }
    __syncthreads();
    #pragma unroll
    for (int kk = 0; kk < 4; ++kk) {
      U4 a; a.u = *(const uint4*)&sm.g.As[(mh * 16 + lr) * 136 + kk * 32 + lg * 8];
      U4 b; b.u = *(const uint4*)&sm.g.Bs[(nh * 16 + lr) * 136 + kk * 32 + lg * 8];
      acc = __builtin_amdgcn_mfma_f32_16x16x32_bf16(a.v, b.v, acc, 0, 0, 0);
    }
    __syncthreads();
  }
  const int n = n0 + nh * 16 + lr;
  const float cb = Cb[n];
  float v[4], prt[4];
  #pragma unroll
  for (int r = 0; r < 4; ++r) {
    v[r] = acc[r] + cb;
    prt[r] = __shfl_xor(v[r], 1, 64);
  }
  if ((lane & 1) == 0) {
    #pragma unroll
    for (int r = 0; r < 4; ++r)
      qk[(size_t)(m0 + mh * 16 + lg * 4 + r) * 256 + (n >> 1)] = pack2(v[r], prt[r]);
  }
}

// ---------------- K2: scores -> softmax -> wp (round-8 proven body) ----------------
__global__ __launch_bounds__(256) void k2_attn(
    const float* __restrict__ pair, const u32* __restrict__ qk,
    u32* __restrict__ wpg) {
  __shared__ u32 PuU[256 * 36];
  __shared__ u32 PtU[64 * 132];
  __shared__ float redz[16][4];
  const int t = threadIdx.x, bi = blockIdx.x;
  const int lane = t & 63, w = t >> 6;
  const int lr = lane & 15, lg = lane >> 4;
  const float* pr = pair + (size_t)bi * 16384;

  #pragma unroll
  for (int r = 0; r < 8; ++r) {
    int task = t + 256 * r;
    int jp = task >> 4, cq = task & 15;
    const float* p0 = pr + (size_t)(2 * jp) * 64 + cq * 4;
    float4 a = *(const float4*)p0;
    float4 b = *(const float4*)(p0 + 64);
    *(uint2*)&PuU[(2 * jp) * 36 + cq * 2]     = make_uint2(pack2(a.x, a.y), pack2(a.z, a.w));
    *(uint2*)&PuU[(2 * jp + 1) * 36 + cq * 2] = make_uint2(pack2(b.x, b.y), pack2(b.z, b.w));
    int c = cq * 4;
    int col = jp ^ ((cq & 7) << 2);
    PtU[(c + 0) * 132 + col] = pack2(a.x, b.x);
    PtU[(c + 1) * 132 + col] = pack2(a.y, b.y);
    PtU[(c + 2) * 132 + col] = pack2(a.z, b.z);
    PtU[(c + 3) * 132 + col] = pack2(a.w, b.w);
  }

  U4 bq0, bq1;
  bq0.u = make_uint4(0, 0, 0, 0); bq1.u = make_uint4(0, 0, 0, 0);
  if (lr < 8) {
    const uint4* qrow = (const uint4*)qk + (size_t)bi * 64 + lr * 8 + lg;
    bq0.u = qrow[0];
    bq1.u = qrow[4];
  }
  __syncthreads();

  f32x4 sc[4];
  #pragma unroll
  for (int jt = 0; jt < 4; ++jt) {
    int j0 = w * 64 + jt * 16;
    U4 a0, a1;
    a0.u = *(const uint4*)&PuU[(j0 + lr) * 36 + lg * 4];
    a1.u = *(const uint4*)&PuU[(j0 + lr) * 36 + 16 + lg * 4];
    f32x4 z = {0.f, 0.f, 0.f, 0.f};
    z = __builtin_amdgcn_mfma_f32_16x16x32_bf16(a0.v, bq0.v, z, 0, 0, 0);
    z = __builtin_amdgcn_mfma_f32_16x16x32_bf16(a1.v, bq1.v, z, 0, 0, 0);
    sc[jt] = z;
  }

  float ev[4][4];
  float es = 0.f;
  #pragma unroll
  for (int jt = 0; jt < 4; ++jt)
    #pragma unroll
    for (int r = 0; r < 4; ++r) { ev[jt][r] = __expf(sc[jt][r]); es += ev[jt][r]; }
  es += __shfl_xor(es, 16, 64);
  es += __shfl_xor(es, 32, 64);
  if (lane < 16) redz[lr][w] = es;
  __syncthreads();
  float4 zr = *(const float4*)&redz[lr][0];
  float rz = __builtin_amdgcn_rcpf(zr.x + zr.y + zr.z + zr.w);
  ushort* wb = (ushort*)PuU;
  #pragma unroll
  for (int jt = 0; jt < 4; ++jt) {
    int j0 = w * 64 + jt * 16 + lg * 4;
    uint2 o = make_uint2(pack2(ev[jt][0] * rz, ev[jt][1] * rz),
                         pack2(ev[jt][2] * rz, ev[jt][3] * rz));
    *(uint2*)&wb[lr * 264 + j0] = o;
  }
  __syncthreads();

  f32x4 wacc = {0.f, 0.f, 0.f, 0.f};
  const int c = w * 16 + lr;
  const int cswz = (c >> 2) & 7;
  #pragma unroll
  for (int ks = 0; ks < 8; ++ks) {
    U4 a; a.u = *(const uint4*)&wb[lr * 264 + ks * 32 + lg * 8];
    int g = ks * 4 + lg;
    U4 b; b.u = *(const uint4*)&PtU[c * 132 + ((g ^ cswz) << 2)];
    wacc = __builtin_amdgcn_mfma_f32_16x16x32_bf16(a.v, b.v, wacc, 0, 0, 0);
  }
  float prt[4];
  #pragma unroll
  for (int r = 0; r < 4; ++r) prt[r] = __shfl_xor(wacc[r], 1, 64);
  if (lane < 32 && (lane & 1) == 0) {
    #pragma unroll
    for (int r = 0; r < 4; ++r) {
      int h = lg * 4 + r;
      wpg[(size_t)bi * 256 + h * 32 + (c >> 1)] = pack2(wacc[r], prt[r]);
    }
  }
}

// ---------------- G2: GP f32 = wp @ Mv, tile 32x32, K=512 ----------------
__global__ __launch_bounds__(256) void k_g2(
    const u32* __restrict__ wp, const u32* __restrict__ MvT,
    float* __restrict__ GP) {
  __shared__ ushort As[32 * 136];
  __shared__ ushort Bs[32 * 136];
  const int t = threadIdx.x;
  const int n0 = blockIdx.x * 32;   // f
  const int m0 = blockIdx.y * 32;   // bi
  const int lane = t & 63, w = t >> 6;
  const int lr = lane & 15, lg = lane >> 4;
  const int mh = w & 1, nh = w >> 1;
  const int row = t >> 3, q = t & 7;
  f32x4 acc = {0.f, 0.f, 0.f, 0.f};
  for (int kc = 0; kc < 4; ++kc) {
    {
      const uint4* A4 = (const uint4*)wp + (size_t)(m0 + row) * 64 + kc * 16 + q * 2;
      *(uint4*)&As[row * 136 + q * 16]     = A4[0];
      *(uint4*)&As[row * 136 + q * 16 + 8] = A4[1];
      const uint4* B4 = (const uint4*)MvT + (size_t)(n0 + row) * 64 + kc * 16 + q * 2;
      *(uint4*)&Bs[row * 136 + q * 16]     = B4[0];
      *(uint4*)&Bs[row * 136 + q * 16 + 8] = B4[1];
    }
    __syncthreads();
    #pragma unroll
    for (int kk = 0; kk < 4; ++kk) {
      U4 a; a.u = *(const uint4*)&As[(mh * 16 + lr) * 136 + kk * 32 + lg * 8];
      U4 b; b.u = *(const uint4*)&Bs[(nh * 16 + lr) * 136 + kk * 32 + lg * 8];
      acc = __builtin_amdgcn_mfma_f32_16x16x32_bf16(a.v, b.v, acc, 0, 0, 0);
    }
    __syncthreads();
  }
  const int n = n0 + nh * 16 + lr;
  #pragma unroll
  for (int r = 0; r < 4; ++r)
    GP[(size_t)(m0 + mh * 16 + lg * 4 + r) * 512 + n] = acc[r];
}

// ---------------- K4: residual + biases + LayerNorm ----------------
__global__ __launch_bounds__(256) void k4_ln(
    const float* __restrict__ GP, const float* __restrict__ bvoP,
    const float* __restrict__ bo, const float* __restrict__ x,
    const float* __restrict__ gamma, const float* __restrict__ beta,
    float* __restrict__ out) {
  __shared__ float red[2][4];
  const int t = threadIdx.x, bi = blockIdx.x;
  const int f = t * 2;
  const size_t base = (size_t)bi * 512 + f;
  float2 y2 = *(const float2*)&GP[base];
  float2 xv = *(const float2*)&x[base];
  float2 bv2 = *(const float2*)&bo[f];
  y2.x += xv.x + bv2.x; y2.y += xv.y + bv2.y;
  #pragma unroll
  for (int h = 0; h < 8; ++h) {
    float2 bp = *(const float2*)&bvoP[h * 512 + f];
    y2.x += bp.x; y2.y += bp.y;
  }
  float s = y2.x + y2.y;
  float q = y2.x * y2.x + y2.y * y2.y;
  for (int o = 32; o; o >>= 1) { s += __shfl_xor(s, o, 64); q += __shfl_xor(q, o, 64); }
  const int wv = t >> 6, lane = t & 63;
  if (lane == 0) { red[0][wv] = s; red[1][wv] = q; }
  __syncthreads();
  float S = red[0][0] + red[0][1] + red[0][2] + red[0][3];
  float Qs = red[1][0] + red[1][1] + red[1][2] + red[1][3];
  float mu = S * (1.f / 512.f);
  float var = Qs * (1.f / 512.f) - mu * mu;
  float rstd = rsqrtf(var + 1e-5f);
  float2 gm = *(const float2*)&gamma[f];
  float2 bt = *(const float2*)&beta[f];
  float2 o2;
  o2.x = (y2.x - mu) * rstd * gm.x + bt.x;
  o2.y = (y2.y - mu) * rstd * gm.y + bt.y;
  *(float2*)&out[base] = o2;
}

extern "C" void kernel_launch(void* const* d_in, const int* in_sizes, int n_in,
                              void* d_out, int out_size, void* d_ws, size_t ws_size,
                              hipStream_t stream) {
  (void)in_sizes; (void)n_in; (void)out_size; (void)ws_size;
  const float* x     = (const float*)d_in[0];
  const float* pair  = (const float*)d_in[1];
  const float* Wq    = (const float*)d_in[2];
  const float* bq    = (const float*)d_in[3];
  const float* Wk    = (const float*)d_in[4];
  // d_in[5] = bk: Q.bk constant over j -> cancels in softmax
  const float* Wv    = (const float*)d_in[6];
  const float* bv    = (const float*)d_in[7];
  const float* Wo    = (const float*)d_in[8];
  const float* bo    = (const float*)d_in[9];
  const float* gamma = (const float*)d_in[10];
  const float* beta  = (const float*)d_in[11];

  float* ws   = (float*)d_ws;
  u32* MkT    = (u32*)ws;
  u32* MvT    = (u32*)ws + 131072;
  float* Cb   = ws + 262144;
  float* bvoP = ws + 262656;
  u32* qk     = (u32*)(ws + 266752);
  u32* wp     = (u32*)(ws + 397824);
  float* GP   = ws + 528896;

  k0_prep<<<64, 256, 0, stream>>>(Wq, bq, Wk, MkT, Cb);
  k_g1<<<320, 256, 0, stream>>>(x, MkT, Cb, Wv, Wo, bv, qk, MvT, bvoP);
  k2_attn<<<512, 256, 0, stream>>>(pair, qk, wp);
  k_g2<<<dim3(16, 16), 256, 0, stream>>>(wp, MvT, GP);
  k4_ln<<<512, 256, 0, stream>>>(GP, bvoP, bo, x, gamma, beta, (float*)d_out);
}

// Round 11
// 30.313 us; speedup vs baseline: 1.6135x; 1.0487x over previous
//
#include <hip/hip_runtime.h>
#include <hip/hip_bf16.h>
#include <stdint.h>

// B=2, L=256, CB=64, D=512, H=8, HD=64. BI = B*L = 512.
// Round-8 configuration (session best: 30.4 us), restored verbatim.
//   K0 (128 blk): MkT[hc][e] bf16 (pre-scaled 0.125), MvT[f][hc] bf16,
//                 Cb[hc] f32 (pre-scaled), bvoP[8][512] f32 (MFMA)
//   G1 (256 blk): qk[bi][hc] bf16 = x @ Mk_s + Cb  (tile 32x32, K=512)
//   K2 (512 blk): per (b,i): pair staged once -> scores MFMA (qk direct bf16)
//                 -> softmax (no max-sub) -> wp MFMA -> shfl-pack bf16 wp
//   G2 (256 blk): GP[bi][f] f32 = wp @ Mv  (tile 32x32, K=512)
//   K4 (512 blk): LayerNorm(GP + bo + sum_h bvoP + x)
//
// ws (f32 offsets): MkT@0 (131072 u32) | MvT@131072 | Cb@262144 | bvoP@262656 |
//   qk@266752 (131072 u32) | wp@397824 (131072 u32) | GP@528896 (262144 f32)

using u32   = unsigned int;
using s8bf  = __attribute__((ext_vector_type(8))) short;
using f32x4 = __attribute__((ext_vector_type(4))) float;

union U4 { uint4 u; s8bf v; };

__device__ __forceinline__ u32 pack2(float a, float b) {
  __hip_bfloat162 h2 = __float22bfloat162_rn(make_float2(a, b));
  union { __hip_bfloat162 h; u32 u; } cv; cv.h = h2; return cv.u;
}
__device__ __forceinline__ ushort bf16r(float f) {
  u32 u = __float_as_uint(f);
  return (ushort)((u + 0x7fffu + ((u >> 16) & 1u)) >> 16);
}
__device__ __forceinline__ float ubf(ushort s) {
  return __uint_as_float(((u32)s) << 16);
}

// ---------------- K0: weight prep (MFMA bf16) ----------------
__global__ __launch_bounds__(256) void k0_prep(
    const float* __restrict__ Wq, const float* __restrict__ bq,
    const float* __restrict__ Wk, const float* __restrict__ Wv,
    const float* __restrict__ Wo, const float* __restrict__ bv,
    u32* __restrict__ MkT, u32* __restrict__ MvT,
    float* __restrict__ Cb, float* __restrict__ bvoP) {
  __shared__ ushort LA[64 * 72];
  __shared__ ushort LB[64 * 72];
  __shared__ float bvec[64];
  const int t = threadIdx.x;
  const int bid = blockIdx.x;
  const bool isMk = bid < 64;
  const int sub = isMk ? bid : bid - 64;
  const int h = sub >> 3;
  const int tile = (sub & 7) * 64;

  {
    int row = t >> 2, q = t & 3;
    const float* Arow = isMk ? (Wq + (size_t)(tile + row) * 512 + h * 64)
                             : (Wv + (size_t)row * 512 + h * 64);
    #pragma unroll
    for (int i = 0; i < 4; ++i) {
      int d0 = q * 4 + i * 16;
      float4 v = *(const float4*)(Arow + d0);
      *(uint2*)&LA[row * 72 + d0] = make_uint2(pack2(v.x, v.y), pack2(v.z, v.w));
    }
  }
  if (isMk) {
    int row = t >> 2, q = t & 3;
    const float* Brow = Wk + (size_t)row * 512 + h * 64;
    #pragma unroll
    for (int i = 0; i < 4; ++i) {
      int d0 = q * 4 + i * 16;
      float4 v = *(const float4*)(Brow + d0);
      *(uint2*)&LB[row * 72 + d0] = make_uint2(pack2(v.x, v.y), pack2(v.z, v.w));
    }
  } else {
    int d = t >> 2, q = t & 3;
    const float* Brow = Wo + (size_t)(h * 64 + d) * 512 + tile;
    #pragma unroll
    for (int i = 0; i < 4; ++i) {
      int f0 = q * 4 + i * 16;
      float4 v = *(const float4*)(Brow + f0);
      LB[(f0 + 0) * 72 + d] = bf16r(v.x);
      LB[(f0 + 1) * 72 + d] = bf16r(v.y);
      LB[(f0 + 2) * 72 + d] = bf16r(v.z);
      LB[(f0 + 3) * 72 + d] = bf16r(v.w);
    }
  }
  if (t < 16) {
    const float* bsrc = isMk ? bq : bv;
    float4 v = *(const float4*)&bsrc[h * 64 + t * 4];
    bvec[t * 4 + 0] = v.x; bvec[t * 4 + 1] = v.y;
    bvec[t * 4 + 2] = v.z; bvec[t * 4 + 3] = v.w;
  }
  __syncthreads();

  const int lane = t & 63, w = t >> 6;
  const int lr = lane & 15, lg = lane >> 4;
  f32x4 acc[4] = {};
  #pragma unroll
  for (int kk = 0; kk < 2; ++kk) {
    U4 a; a.u = *(const uint4*)&LA[(w * 16 + lr) * 72 + kk * 32 + lg * 8];
    #pragma unroll
    for (int nt = 0; nt < 4; ++nt) {
      U4 b; b.u = *(const uint4*)&LB[(nt * 16 + lr) * 72 + kk * 32 + lg * 8];
      acc[nt] = __builtin_amdgcn_mfma_f32_16x16x32_bf16(a.v, b.v, acc[nt], 0, 0, 0);
    }
  }
  if (isMk) {
    #pragma unroll
    for (int nt = 0; nt < 4; ++nt) {
      int hc = h * 64 + nt * 16 + lr;
      int e0 = tile + w * 16 + lg * 4;
      uint2 o = make_uint2(pack2(acc[nt][0] * 0.125f, acc[nt][1] * 0.125f),
                           pack2(acc[nt][2] * 0.125f, acc[nt][3] * 0.125f));
      *(uint2*)&MkT[(size_t)hc * 256 + (e0 >> 1)] = o;
    }
    if ((sub & 7) == 0 && t < 64) {
      float s = 0.f;
      #pragma unroll 16
      for (int d = 0; d < 64; ++d) s += bvec[d] * ubf(LB[t * 72 + d]);
      Cb[h * 64 + t] = s * 0.125f;
    }
  } else {
    #pragma unroll
    for (int nt = 0; nt < 4; ++nt) {
      int f = tile + nt * 16 + lr;
      int hc0 = h * 64 + w * 16 + lg * 4;
      uint2 o = make_uint2(pack2(acc[nt][0], acc[nt][1]),
                           pack2(acc[nt][2], acc[nt][3]));
      *(uint2*)&MvT[(size_t)f * 256 + (hc0 >> 1)] = o;
    }
    if (t < 64) {
      float s = 0.f;
      #pragma unroll 16
      for (int d = 0; d < 64; ++d) s += bvec[d] * ubf(LB[t * 72 + d]);
      bvoP[h * 512 + tile + t] = s;
    }
  }
}

// ---------------- G1: qk bf16 = x @ Mk_s + Cb, tile 32x32, K=512 ----------------
// grid (16 hc-tiles, 16 bi-tiles) = 256 blocks
__global__ __launch_bounds__(256) void k_g1(
    const float* __restrict__ x, const u32* __restrict__ MkT,
    const float* __restrict__ Cb, u32* __restrict__ qk) {
  __shared__ ushort As[32 * 136];
  __shared__ ushort Bs[32 * 136];
  const int t = threadIdx.x;
  const int n0 = blockIdx.x * 32;   // hc
  const int m0 = blockIdx.y * 32;   // bi
  const int lane = t & 63, w = t >> 6;
  const int lr = lane & 15, lg = lane >> 4;
  const int mh = w & 1, nh = w >> 1;
  const int row = t >> 3, q = t & 7;
  f32x4 acc = {0.f, 0.f, 0.f, 0.f};
  for (int kc = 0; kc < 4; ++kc) {
    { // A: x rows m0..+32, cols kc*128..+128, fp32 -> bf16 (16 f32/thread)
      const float* xp = x + (size_t)(m0 + row) * 512 + kc * 128 + q * 16;
      float4 v0 = *(const float4*)xp,       v1 = *(const float4*)(xp + 4);
      float4 v2 = *(const float4*)(xp + 8), v3 = *(const float4*)(xp + 12);
      *(uint4*)&As[row * 136 + q * 16] =
          make_uint4(pack2(v0.x, v0.y), pack2(v0.z, v0.w),
                     pack2(v1.x, v1.y), pack2(v1.z, v1.w));
      *(uint4*)&As[row * 136 + q * 16 + 8] =
          make_uint4(pack2(v2.x, v2.y), pack2(v2.z, v2.w),
                     pack2(v3.x, v3.y), pack2(v3.z, v3.w));
    }
    { // B: MkT rows n0..+32, u32 cols kc*64..+64 (8 u32/thread)
      const uint4* B4 = (const uint4*)MkT + (size_t)(n0 + row) * 64 + kc * 16 + q * 2;
      *(uint4*)&Bs[row * 136 + q * 16]     = B4[0];
      *(uint4*)&Bs[row * 136 + q * 16 + 8] = B4[1];
    }
    __syncthreads();
    #pragma unroll
    for (int kk = 0; kk < 4; ++kk) {
      U4 a; a.u = *(const uint4*)&As[(mh * 16 + lr) * 136 + kk * 32 + lg * 8];
      U4 b; b.u = *(const uint4*)&Bs[(nh * 16 + lr) * 136 + kk * 32 + lg * 8];
      acc = __builtin_amdgcn_mfma_f32_16x16x32_bf16(a.v, b.v, acc, 0, 0, 0);
    }
    __syncthreads();
  }
  const int n = n0 + nh * 16 + lr;
  const float cb = Cb[n];
  float v[4], prt[4];
  #pragma unroll
  for (int r = 0; r < 4; ++r) {
    v[r] = acc[r] + cb;
    prt[r] = __shfl_xor(v[r], 1, 64);
  }
  if ((lane & 1) == 0) {
    #pragma unroll
    for (int r = 0; r < 4; ++r)
      qk[(size_t)(m0 + mh * 16 + lg * 4 + r) * 256 + (n >> 1)] = pack2(v[r], prt[r]);
  }
}

// ---------------- K2: scores -> softmax -> wp (bf16 qk) ----------------
__global__ __launch_bounds__(256) void k2_attn(
    const float* __restrict__ pair, const u32* __restrict__ qk,
    u32* __restrict__ wpg) {
  __shared__ u32 PuU[256 * 36];
  __shared__ u32 PtU[64 * 132];
  __shared__ float redz[16][4];
  const int t = threadIdx.x, bi = blockIdx.x;
  const int lane = t & 63, w = t >> 6;
  const int lr = lane & 15, lg = lane >> 4;
  const float* pr = pair + (size_t)bi * 16384;

  #pragma unroll
  for (int r = 0; r < 8; ++r) {
    int task = t + 256 * r;
    int jp = task >> 4, cq = task & 15;
    const float* p0 = pr + (size_t)(2 * jp) * 64 + cq * 4;
    float4 a = *(const float4*)p0;
    float4 b = *(const float4*)(p0 + 64);
    *(uint2*)&PuU[(2 * jp) * 36 + cq * 2]     = make_uint2(pack2(a.x, a.y), pack2(a.z, a.w));
    *(uint2*)&PuU[(2 * jp + 1) * 36 + cq * 2] = make_uint2(pack2(b.x, b.y), pack2(b.z, b.w));
    int c = cq * 4;
    int col = jp ^ ((cq & 7) << 2);
    PtU[(c + 0) * 132 + col] = pack2(a.x, b.x);
    PtU[(c + 1) * 132 + col] = pack2(a.y, b.y);
    PtU[(c + 2) * 132 + col] = pack2(a.z, b.z);
    PtU[(c + 3) * 132 + col] = pack2(a.w, b.w);
  }

  // qk B-frags: direct bf16 loads (row bi = 256 u32 = 64 uint4)
  U4 bq0, bq1;
  bq0.u = make_uint4(0, 0, 0, 0); bq1.u = make_uint4(0, 0, 0, 0);
  if (lr < 8) {
    const uint4* qrow = (const uint4*)qk + (size_t)bi * 64 + lr * 8 + lg;
    bq0.u = qrow[0];
    bq1.u = qrow[4];
  }
  __syncthreads();

  f32x4 sc[4];
  #pragma unroll
  for (int jt = 0; jt < 4; ++jt) {
    int j0 = w * 64 + jt * 16;
    U4 a0, a1;
    a0.u = *(const uint4*)&PuU[(j0 + lr) * 36 + lg * 4];
    a1.u = *(const uint4*)&PuU[(j0 + lr) * 36 + 16 + lg * 4];
    f32x4 z = {0.f, 0.f, 0.f, 0.f};
    z = __builtin_amdgcn_mfma_f32_16x16x32_bf16(a0.v, bq0.v, z, 0, 0, 0);
    z = __builtin_amdgcn_mfma_f32_16x16x32_bf16(a1.v, bq1.v, z, 0, 0, 0);
    sc[jt] = z;
  }

  float ev[4][4];
  float es = 0.f;
  #pragma unroll
  for (int jt = 0; jt < 4; ++jt)
    #pragma unroll
    for (int r = 0; r < 4; ++r) { ev[jt][r] = __expf(sc[jt][r]); es += ev[jt][r]; }
  es += __shfl_xor(es, 16, 64);
  es += __shfl_xor(es, 32, 64);
  if (lane < 16) redz[lr][w] = es;
  __syncthreads();
  float4 zr = *(const float4*)&redz[lr][0];
  float rz = __builtin_amdgcn_rcpf(zr.x + zr.y + zr.z + zr.w);
  ushort* wb = (ushort*)PuU;
  #pragma unroll
  for (int jt = 0; jt < 4; ++jt) {
    int j0 = w * 64 + jt * 16 + lg * 4;
    uint2 o = make_uint2(pack2(ev[jt][0] * rz, ev[jt][1] * rz),
                         pack2(ev[jt][2] * rz, ev[jt][3] * rz));
    *(uint2*)&wb[lr * 264 + j0] = o;
  }
  __syncthreads();

  f32x4 wacc = {0.f, 0.f, 0.f, 0.f};
  const int c = w * 16 + lr;
  const int cswz = (c >> 2) & 7;
  #pragma unroll
  for (int ks = 0; ks < 8; ++ks) {
    U4 a; a.u = *(const uint4*)&wb[lr * 264 + ks * 32 + lg * 8];
    int g = ks * 4 + lg;
    U4 b; b.u = *(const uint4*)&PtU[c * 132 + ((g ^ cswz) << 2)];
    wacc = __builtin_amdgcn_mfma_f32_16x16x32_bf16(a.v, b.v, wacc, 0, 0, 0);
  }
  float prt[4];
  #pragma unroll
  for (int r = 0; r < 4; ++r) prt[r] = __shfl_xor(wacc[r], 1, 64);
  if (lane < 32 && (lane & 1) == 0) {
    #pragma unroll
    for (int r = 0; r < 4; ++r) {
      int h = lg * 4 + r;
      wpg[(size_t)bi * 256 + h * 32 + (c >> 1)] = pack2(wacc[r], prt[r]);
    }
  }
}

// ---------------- G2: GP f32 = wp @ Mv, tile 32x32, K=512 ----------------
// grid (16 f-tiles, 16 bi-tiles) = 256 blocks
__global__ __launch_bounds__(256) void k_g2(
    const u32* __restrict__ wp, const u32* __restrict__ MvT,
    float* __restrict__ GP) {
  __shared__ ushort As[32 * 136];
  __shared__ ushort Bs[32 * 136];
  const int t = threadIdx.x;
  const int n0 = blockIdx.x * 32;   // f
  const int m0 = blockIdx.y * 32;   // bi
  const int lane = t & 63, w = t >> 6;
  const int lr = lane & 15, lg = lane >> 4;
  const int mh = w & 1, nh = w >> 1;
  const int row = t >> 3, q = t & 7;
  f32x4 acc = {0.f, 0.f, 0.f, 0.f};
  for (int kc = 0; kc < 4; ++kc) {
    {
      const uint4* A4 = (const uint4*)wp + (size_t)(m0 + row) * 64 + kc * 16 + q * 2;
      *(uint4*)&As[row * 136 + q * 16]     = A4[0];
      *(uint4*)&As[row * 136 + q * 16 + 8] = A4[1];
      const uint4* B4 = (const uint4*)MvT + (size_t)(n0 + row) * 64 + kc * 16 + q * 2;
      *(uint4*)&Bs[row * 136 + q * 16]     = B4[0];
      *(uint4*)&Bs[row * 136 + q * 16 + 8] = B4[1];
    }
    __syncthreads();
    #pragma unroll
    for (int kk = 0; kk < 4; ++kk) {
      U4 a; a.u = *(const uint4*)&As[(mh * 16 + lr) * 136 + kk * 32 + lg * 8];
      U4 b; b.u = *(const uint4*)&Bs[(nh * 16 + lr) * 136 + kk * 32 + lg * 8];
      acc = __builtin_amdgcn_mfma_f32_16x16x32_bf16(a.v, b.v, acc, 0, 0, 0);
    }
    __syncthreads();
  }
  const int n = n0 + nh * 16 + lr;
  #pragma unroll
  for (int r = 0; r < 4; ++r)
    GP[(size_t)(m0 + mh * 16 + lg * 4 + r) * 512 + n] = acc[r];
}

// ---------------- K4: residual + biases + LayerNorm ----------------
__global__ __launch_bounds__(256) void k4_ln(
    const float* __restrict__ GP, const float* __restrict__ bvoP,
    const float* __restrict__ bo, const float* __restrict__ x,
    const float* __restrict__ gamma, const float* __restrict__ beta,
    float* __restrict__ out) {
  __shared__ float red[2][4];
  const int t = threadIdx.x, bi = blockIdx.x;
  const int f = t * 2;
  const size_t base = (size_t)bi * 512 + f;
  float2 y2 = *(const float2*)&GP[base];
  float2 xv = *(const float2*)&x[base];
  float2 bv2 = *(const float2*)&bo[f];
  y2.x += xv.x + bv2.x; y2.y += xv.y + bv2.y;
  #pragma unroll
  for (int h = 0; h < 8; ++h) {
    float2 bp = *(const float2*)&bvoP[h * 512 + f];
    y2.x += bp.x; y2.y += bp.y;
  }
  float s = y2.x + y2.y;
  float q = y2.x * y2.x + y2.y * y2.y;
  for (int o = 32; o; o >>= 1) { s += __shfl_xor(s, o, 64); q += __shfl_xor(q, o, 64); }
  const int wv = t >> 6, lane = t & 63;
  if (lane == 0) { red[0][wv] = s; red[1][wv] = q; }
  __syncthreads();
  float S = red[0][0] + red[0][1] + red[0][2] + red[0][3];
  float Qs = red[1][0] + red[1][1] + red[1][2] + red[1][3];
  float mu = S * (1.f / 512.f);
  float var = Qs * (1.f / 512.f) - mu * mu;
  float rstd = rsqrtf(var + 1e-5f);
  float2 gm = *(const float2*)&gamma[f];
  float2 bt = *(const float2*)&beta[f];
  float2 o2;
  o2.x = (y2.x - mu) * rstd * gm.x + bt.x;
  o2.y = (y2.y - mu) * rstd * gm.y + bt.y;
  *(float2*)&out[base] = o2;
}

extern "C" void kernel_launch(void* const* d_in, const int* in_sizes, int n_in,
                              void* d_out, int out_size, void* d_ws, size_t ws_size,
                              hipStream_t stream) {
  (void)in_sizes; (void)n_in; (void)out_size; (void)ws_size;
  const float* x     = (const float*)d_in[0];
  const float* pair  = (const float*)d_in[1];
  const float* Wq    = (const float*)d_in[2];
  const float* bq    = (const float*)d_in[3];
  const float* Wk    = (const float*)d_in[4];
  // d_in[5] = bk: Q.bk constant over j -> cancels in softmax
  const float* Wv    = (const float*)d_in[6];
  const float* bv    = (const float*)d_in[7];
  const float* Wo    = (const float*)d_in[8];
  const float* bo    = (const float*)d_in[9];
  const float* gamma = (const float*)d_in[10];
  const float* beta  = (const float*)d_in[11];

  float* ws   = (float*)d_ws;
  u32* MkT    = (u32*)ws;
  u32* MvT    = (u32*)ws + 131072;
  float* Cb   = ws + 262144;
  float* bvoP = ws + 262656;
  u32* qk     = (u32*)(ws + 266752);
  u32* wp     = (u32*)(ws + 397824);
  float* GP   = ws + 528896;

  k0_prep<<<128, 256, 0, stream>>>(Wq, bq, Wk, Wv, Wo, bv, MkT, MvT, Cb, bvoP);
  k_g1<<<dim3(16, 16), 256, 0, stream>>>(x, MkT, Cb, qk);
  k2_attn<<<512, 256, 0, stream>>>(pair, qk, wp);
  k_g2<<<dim3(16, 16), 256, 0, stream>>>(wp, MvT, GP);
  k4_ln<<<512, 256, 0, stream>>>(GP, bvoP, bo, x, gamma, beta, (float*)d_out);
}